// Round 14
// baseline (2069.460 us; speedup 1.0000x reference)
//
#include <hip/hip_runtime.h>

#define N_NODES_C 50000
#define SEQ_LEN_C 32
#define VOCAB_C 50000
#define EMBED_C 300
#define NHID_C 128
#define NGATE_C 512
#define N_EDGES_C 800000

typedef __attribute__((ext_vector_type(8))) short s16x8;
typedef __attribute__((ext_vector_type(16))) float f32x16;

#define LOG2E_C 1.442695040888963f

__device__ __forceinline__ unsigned f2bf(float x) {
    unsigned u = __float_as_uint(x);
    return (u + 0x7fffu + ((u >> 16) & 1u)) >> 16;
}
__device__ __forceinline__ float bf2f(unsigned h) { return __uint_as_float(h << 16); }
__device__ __forceinline__ float bflo(unsigned u) { return __uint_as_float(u << 16); }
__device__ __forceinline__ float bfhi(unsigned u) { return __uint_as_float(u & 0xffff0000u); }
__device__ __forceinline__ float rcp_f(float x) { return __builtin_amdgcn_rcpf(x); }
__device__ __forceinline__ float exp2_f(float x) { return __builtin_amdgcn_exp2f(x); }
__device__ __forceinline__ unsigned cvt_pk_bf16(float a, float b) {
    unsigned r;
    asm("v_cvt_pk_bf16_f32 %0, %1, %2" : "=v"(r) : "v"(a), "v"(b));
    return r;
}

// Gate-row permutation (k_table T layout + k_lstm Whh frags), 32x32 tiles:
// tile gt, row-in-tile rr: gate = rr&3, hh = rr>>2,
// hid = (gt>>1)*16 + (hh&1)*8 + (gt&1)*4 + (hh>>1), g_orig = gate*128 + hid.
// T slot layout is READER-register-ordered: slot(gt, hi, r) = gt*32 + hi*16 + r,
// where acc reg r of reader lane (lo,hi) is gate-row rr = (r&3) + 8*(r>>2) + 4*hi.
// => writer: off_c = gt*32 + ((hid>>3)&1)*16 + gate + 4*(hid&3).
// Reader loads 2 contiguous dwordx4 per tile (32B/lane).

// ---------------------------------------------------------------------------
// Phase 1: T[v] = permuted bf16 of emb[v] @ Wih^T + b. grid (391,2), 256 thr.
// LDS-staged: scattered 2B results land in LDS (cheap bank conflicts), then
// flushed as coalesced 16B stores -- the direct 2B global scatter touched ~32
// cache lines per store instruction (L2-transaction + partial-line bound).
// ---------------------------------------------------------------------------
__global__ __launch_bounds__(256) void k_table(
    const float* __restrict__ emb,
    const float* __restrict__ WihF, const float* __restrict__ bF,
    const float* __restrict__ WihB, const float* __restrict__ bB,
    unsigned short* __restrict__ TF, unsigned short* __restrict__ TB)
{
    extern __shared__ unsigned short tl[];   // 128 rows x 512 cols = 128KB
    const int dir = blockIdx.y;
    const float* __restrict__ Wih  = dir ? WihB : WihF;
    const float* __restrict__ bias = dir ? bB : bF;
    unsigned short* __restrict__ T = dir ? TB : TF;

    const int tid = threadIdx.x;
    const int lane = tid & 63;
    const int lo = lane & 31, hi = lane >> 5;
    const int wv = tid >> 6;
    const int vbase = blockIdx.x * 128 + wv * 32;
    int vr = vbase + lo;
    if (vr >= VOCAB_C) vr = VOCAB_C - 1;

    s16x8 afr[19];
    #pragma unroll
    for (int kt = 0; kt < 19; ++kt) {
        const int k = kt * 16 + hi * 8;
        const float* src = emb + vr * EMBED_C + k;
        float4 a = *(const float4*)src;
        float4 b = (k + 8 <= EMBED_C) ? *(const float4*)(src + 4)
                                      : make_float4(0.f, 0.f, 0.f, 0.f);
        s16x8 f;
        f[0] = (short)f2bf(a.x); f[1] = (short)f2bf(a.y);
        f[2] = (short)f2bf(a.z); f[3] = (short)f2bf(a.w);
        f[4] = (short)f2bf(b.x); f[5] = (short)f2bf(b.y);
        f[6] = (short)f2bf(b.z); f[7] = (short)f2bf(b.w);
        afr[kt] = f;
    }

    for (int nt = 0; nt < 16; ++nt) {
        const int g = nt * 32 + lo;
        const float bv = bias[g];
        const int gate = g >> 7, hid = g & 127;
        const int gt = (hid >> 4) * 2 + ((hid >> 2) & 1);
        const int off_c = gt * 32 + ((hid >> 3) & 1) * 16 + gate + 4 * (hid & 3);
        f32x16 acc;
        #pragma unroll
        for (int r = 0; r < 16; ++r) acc[r] = bv;
        #pragma unroll
        for (int kt = 0; kt < 19; ++kt) {
            const int k = kt * 16 + hi * 8;
            const float* src = Wih + g * EMBED_C + k;
            float4 a = *(const float4*)src;
            float4 b = (k + 8 <= EMBED_C) ? *(const float4*)(src + 4)
                                          : make_float4(0.f, 0.f, 0.f, 0.f);
            s16x8 w;
            w[0] = (short)f2bf(a.x); w[1] = (short)f2bf(a.y);
            w[2] = (short)f2bf(a.z); w[3] = (short)f2bf(a.w);
            w[4] = (short)f2bf(b.x); w[5] = (short)f2bf(b.y);
            w[6] = (short)f2bf(b.z); w[7] = (short)f2bf(b.w);
            acc = __builtin_amdgcn_mfma_f32_32x32x16_bf16(afr[kt], w, acc, 0, 0, 0);
        }
        #pragma unroll
        for (int r = 0; r < 16; ++r) {
            const int row = wv * 32 + (r & 3) + 8 * (r >> 2) + 4 * hi;
            tl[row * NGATE_C + off_c] = (unsigned short)f2bf(acc[r]);
        }
    }
    __syncthreads();

    // coalesced flush: 128 rows x 64 chunks of 8 ushort (16B)
    const int vb0 = blockIdx.x * 128;
    for (int idx = tid; idx < 8192; idx += 256) {
        const int row = idx >> 6;
        const int c16 = idx & 63;
        const int v = vb0 + row;
        if (v < VOCAB_C) {
            *(uint4*)(T + (size_t)v * NGATE_C + c16 * 8)
                = *(const uint4*)(tl + row * NGATE_C + c16 * 8);
        }
    }
}

// ---------------------------------------------------------------------------
// Phase 2: persistent LSTM (R8 structure + 7-trans gate math). 1024 thr =
// 16 waves x 32 nodes, grid (98,2). waves_per_eu(4,4). dwordx4 T-gather with
// depth-1 prefetch. c as packed bf16 pairs. [plateaued ~950us]
// ---------------------------------------------------------------------------
__global__ __launch_bounds__(1024)
__attribute__((amdgpu_waves_per_eu(4, 4)))
void k_lstm(
    const int* __restrict__ sentence,
    const float* __restrict__ WhhF, const float* __restrict__ WhhB,
    const unsigned short* __restrict__ TF, const unsigned short* __restrict__ TB,
    float* __restrict__ X)
{
    extern __shared__ unsigned short lds[]; // 8192 slots * 16B = 128KB
    const int dir = blockIdx.y;
    const float* __restrict__ Whh = dir ? WhhB : WhhF;
    const unsigned short* __restrict__ T = dir ? TB : TF;
    const int tid = threadIdx.x;

    for (int s = tid; s < 8192; s += 1024) {
        const int ls = s & 63;
        const int gt = (s >> 6) & 15;
        const int kt = s >> 10;
        const int rr = ls & 31, khalf = ls >> 5;
        const int gate = rr & 3, hh = rr >> 2;
        const int hid = (gt >> 1) * 16 + (hh & 1) * 8 + (gt & 1) * 4 + (hh >> 1);
        const int g_orig = gate * NHID_C + hid;
        const int k = kt * 16 + khalf * 8;
        const float* src = Whh + g_orig * NHID_C + k;
        float4 a = *(const float4*)src;
        float4 b = *(const float4*)(src + 4);
        uint4 pk;
        pk.x = f2bf(a.x) | (f2bf(a.y) << 16);
        pk.y = f2bf(a.z) | (f2bf(a.w) << 16);
        pk.z = f2bf(b.x) | (f2bf(b.y) << 16);
        pk.w = f2bf(b.z) | (f2bf(b.w) << 16);
        *(uint4*)(lds + s * 8) = pk;
    }
    __syncthreads();

    const int lane = tid & 63;
    const int lo = lane & 31, hi = lane >> 5;
    const int node = blockIdx.x * 512 + (tid >> 6) * 32 + lo;
    const int nv = node < N_NODES_C ? node : 0;
    const int* __restrict__ sent = sentence + nv * SEQ_LEN_C;

    s16x8 hfr[8];
    #pragma unroll
    for (int kt = 0; kt < 8; ++kt) {
        #pragma unroll
        for (int j = 0; j < 8; ++j) hfr[kt][j] = 0;
    }
    unsigned cpk[32];
    #pragma unroll
    for (int r = 0; r < 32; ++r) cpk[r] = 0u;

    int wd = sent[dir ? 31 : 0];
    int wn = sent[dir ? 30 : 1];

    uint4 pf0, pf1;
    {
        const unsigned short* tr0 = T + (size_t)wd * NGATE_C + hi * 16;
        pf0 = *(const uint4*)(tr0);
        pf1 = *(const uint4*)(tr0 + 8);
    }

    for (int t = 0; t < SEQ_LEN_C - 1; ++t) {
        const unsigned short* trow = T + (size_t)wd * NGATE_C;
        const unsigned short* nrow = T + (size_t)wn * NGATE_C;
        wd = wn;
        const int nt2 = (t + 2 <= SEQ_LEN_C - 1) ? t + 2 : SEQ_LEN_C - 1;
        wn = sent[dir ? (SEQ_LEN_C - 1 - nt2) : nt2];
        uint4 nhf[8];

        #pragma unroll
        for (int gt = 0; gt < 16; ++gt) {
            f32x16 acc;
            acc[0]  = bflo(pf0.x); acc[1]  = bfhi(pf0.x);
            acc[2]  = bflo(pf0.y); acc[3]  = bfhi(pf0.y);
            acc[4]  = bflo(pf0.z); acc[5]  = bfhi(pf0.z);
            acc[6]  = bflo(pf0.w); acc[7]  = bfhi(pf0.w);
            acc[8]  = bflo(pf1.x); acc[9]  = bfhi(pf1.x);
            acc[10] = bflo(pf1.y); acc[11] = bfhi(pf1.y);
            acc[12] = bflo(pf1.z); acc[13] = bfhi(pf1.z);
            acc[14] = bflo(pf1.w); acc[15] = bfhi(pf1.w);
            const unsigned short* nsrc =
                ((gt < 15) ? (trow + (gt + 1) * 32) : nrow) + hi * 16;
            pf0 = *(const uint4*)(nsrc);
            pf1 = *(const uint4*)(nsrc + 8);

            #pragma unroll
            for (int kt = 0; kt < 8; ++kt) {
                const s16x8 af = *(const s16x8*)(lds + ((kt * 16 + gt) * 64 + lane) * 8);
                acc = __builtin_amdgcn_mfma_f32_32x32x16_bf16(af, hfr[kt], acc, 0, 0, 0);
            }

            const unsigned cp0 = cpk[gt * 2 + 0];
            const unsigned cp1 = cpk[gt * 2 + 1];
            const float cc[4] = {bflo(cp0), bfhi(cp0), bflo(cp1), bfhi(cp1)};
            float hn[4], cn[4];
            #pragma unroll
            for (int m = 0; m < 4; ++m) {
                const float iv = acc[4 * m + 0], fv = acc[4 * m + 1];
                const float gv = acc[4 * m + 2], ov = acc[4 * m + 3];
                const float a  = exp2_f(fv * -LOG2E_C);
                const float b  = exp2_f(iv * -LOG2E_C);
                const float G  = exp2_f(gv * (2.0f * LOG2E_C));
                const float oa = exp2_f(ov * -LOG2E_C);
                const float pa = 1.0f + a, pb = 1.0f + b;
                const float Gp = G + 1.0f, Gm = G - 1.0f;
                const float t0 = pb * Gp;
                const float num = __builtin_fmaf(cc[m], t0, pa * Gm);
                const float den = pa * t0;
                cn[m] = num * rcp_f(den);
                const float C  = exp2_f(cn[m] * (2.0f * LOG2E_C));
                hn[m] = (C - 1.0f) * rcp_f((1.0f + oa) * (C + 1.0f));
            }
            cpk[gt * 2 + 0] = cvt_pk_bf16(cn[0], cn[1]);
            cpk[gt * 2 + 1] = cvt_pk_bf16(cn[2], cn[3]);
            const unsigned w0 = cvt_pk_bf16(hn[0], hn[1]);
            const unsigned w1 = cvt_pk_bf16(hn[2], hn[3]);
            if ((gt & 1) == 0) { nhf[gt >> 1].x = w0; nhf[gt >> 1].y = w1; }
            else               { nhf[gt >> 1].z = w0; nhf[gt >> 1].w = w1; }
        }
        #pragma unroll
        for (int kt = 0; kt < 8; ++kt) hfr[kt] = *(s16x8*)&nhf[kt];
    }

    {
        const unsigned short* trow = T + (size_t)wd * NGATE_C;
        #pragma unroll
        for (int gt = 0; gt < 16; ++gt) {
            f32x16 acc;
            acc[0]  = bflo(pf0.x); acc[1]  = bfhi(pf0.x);
            acc[2]  = bflo(pf0.y); acc[3]  = bfhi(pf0.y);
            acc[4]  = bflo(pf0.z); acc[5]  = bfhi(pf0.z);
            acc[6]  = bflo(pf0.w); acc[7]  = bfhi(pf0.w);
            acc[8]  = bflo(pf1.x); acc[9]  = bfhi(pf1.x);
            acc[10] = bflo(pf1.y); acc[11] = bfhi(pf1.y);
            acc[12] = bflo(pf1.z); acc[13] = bfhi(pf1.z);
            acc[14] = bflo(pf1.w); acc[15] = bfhi(pf1.w);
            if (gt < 15) {
                const unsigned short* nsrc = trow + (gt + 1) * 32 + hi * 16;
                pf0 = *(const uint4*)(nsrc);
                pf1 = *(const uint4*)(nsrc + 8);
            }
            #pragma unroll
            for (int kt = 0; kt < 8; ++kt) {
                const s16x8 af = *(const s16x8*)(lds + ((kt * 16 + gt) * 64 + lane) * 8);
                acc = __builtin_amdgcn_mfma_f32_32x32x16_bf16(af, hfr[kt], acc, 0, 0, 0);
            }

            const unsigned cp0 = cpk[gt * 2 + 0];
            const unsigned cp1 = cpk[gt * 2 + 1];
            const float cc[4] = {bflo(cp0), bfhi(cp0), bflo(cp1), bfhi(cp1)};
            float hn[4];
            #pragma unroll
            for (int m = 0; m < 4; ++m) {
                const float iv = acc[4 * m + 0], fv = acc[4 * m + 1];
                const float gv = acc[4 * m + 2], ov = acc[4 * m + 3];
                const float a  = exp2_f(fv * -LOG2E_C);
                const float b  = exp2_f(iv * -LOG2E_C);
                const float G  = exp2_f(gv * (2.0f * LOG2E_C));
                const float oa = exp2_f(ov * -LOG2E_C);
                const float pa = 1.0f + a, pb = 1.0f + b;
                const float Gp = G + 1.0f, Gm = G - 1.0f;
                const float t0 = pb * Gp;
                const float num = __builtin_fmaf(cc[m], t0, pa * Gm);
                const float den = pa * t0;
                const float cnv = num * rcp_f(den);
                const float C  = exp2_f(cnv * (2.0f * LOG2E_C));
                hn[m] = (C - 1.0f) * rcp_f((1.0f + oa) * (C + 1.0f));
            }
            if (node < N_NODES_C) {
                *(float4*)(X + (size_t)node * 256 + dir * NHID_C
                           + (gt >> 1) * 16 + hi * 8 + (gt & 1) * 4)
                    = make_float4(hn[0], hn[1], hn[2], hn[3]);
            }
        }
    }
}

// ---------------------------------------------------------------------------
// Phase 3a: xw1 = X @ W1, split-bf16 (hi/lo) 3-MFMA. (unchanged)
// ---------------------------------------------------------------------------
__global__ __launch_bounds__(256) void k_gcn1(
    const float* __restrict__ X, const float* __restrict__ W1, float* __restrict__ xw1)
{
    extern __shared__ unsigned short lds[];
    const int tid = threadIdx.x;
    for (int idx = tid; idx < 4096; idx += 256) {
        const int kt = idx >> 8, nt = (idx >> 6) & 3, ls = idx & 63;
        const int k0 = kt * 16 + (ls >> 5) * 8;
        const int j = nt * 32 + (ls & 31);
        unsigned ph[8], pl[8];
        #pragma unroll
        for (int jj = 0; jj < 8; ++jj) {
            const float w = W1[(k0 + jj) * NHID_C + j];
            const unsigned wh = f2bf(w);
            ph[jj] = wh;
            pl[jj] = f2bf(w - bf2f(wh));
        }
        uint4 vh, vl;
        vh.x = ph[0] | (ph[1] << 16); vh.y = ph[2] | (ph[3] << 16);
        vh.z = ph[4] | (ph[5] << 16); vh.w = ph[6] | (ph[7] << 16);
        vl.x = pl[0] | (pl[1] << 16); vl.y = pl[2] | (pl[3] << 16);
        vl.z = pl[4] | (pl[5] << 16); vl.w = pl[6] | (pl[7] << 16);
        *(uint4*)(lds + idx * 8) = vh;
        *(uint4*)(lds + (4096 + idx) * 8) = vl;
    }
    __syncthreads();

    const int lane = tid & 63, lo = lane & 31, hi = lane >> 5;
    const int nbase = blockIdx.x * 128 + (tid >> 6) * 32;
    int nr = nbase + lo;
    if (nr >= N_NODES_C) nr = N_NODES_C - 1;

    f32x16 acc[4];
    #pragma unroll
    for (int nt = 0; nt < 4; ++nt) {
        #pragma unroll
        for (int r = 0; r < 16; ++r) acc[nt][r] = 0.f;
    }

    for (int kt = 0; kt < 16; ++kt) {
        const float* src = X + (size_t)nr * 256 + kt * 16 + hi * 8;
        float4 a = *(const float4*)src;
        float4 b = *(const float4*)(src + 4);
        float xv[8] = {a.x, a.y, a.z, a.w, b.x, b.y, b.z, b.w};
        s16x8 xh, xl;
        #pragma unroll
        for (int jj = 0; jj < 8; ++jj) {
            const unsigned h = f2bf(xv[jj]);
            xh[jj] = (short)h;
            xl[jj] = (short)f2bf(xv[jj] - bf2f(h));
        }
        #pragma unroll
        for (int nt = 0; nt < 4; ++nt) {
            const int slot = (kt * 4 + nt) * 64 + lane;
            const s16x8 bh = *(const s16x8*)(lds + slot * 8);
            const s16x8 bl = *(const s16x8*)(lds + (4096 + slot) * 8);
            acc[nt] = __builtin_amdgcn_mfma_f32_32x32x16_bf16(xh, bh, acc[nt], 0, 0, 0);
            acc[nt] = __builtin_amdgcn_mfma_f32_32x32x16_bf16(xl, bh, acc[nt], 0, 0, 0);
            acc[nt] = __builtin_amdgcn_mfma_f32_32x32x16_bf16(xh, bl, acc[nt], 0, 0, 0);
        }
    }
    #pragma unroll
    for (int nt = 0; nt < 4; ++nt) {
        #pragma unroll
        for (int r = 0; r < 16; ++r) {
            const int n = nbase + (r & 3) + 8 * (r >> 2) + 4 * hi;
            if (n < N_NODES_C) xw1[(size_t)n * NHID_C + nt * 32 + lo] = acc[nt][r];
        }
    }
}

// Phase 3b: scatter-add xw1[src] into agg1[dst].
__global__ void k_scatter1(const float* __restrict__ xw1, const int* __restrict__ ei,
                           float* __restrict__ agg)
{
    const int e = blockIdx.x * 4 + (threadIdx.x >> 6);
    if (e >= N_EDGES_C) return;
    const int lane = threadIdx.x & 63;
    const int src = ei[e], dst = ei[N_EDGES_C + e];
    const float2 v = *(const float2*)(xw1 + (size_t)src * NHID_C + lane * 2);
    atomicAdd(&agg[(size_t)dst * NHID_C + lane * 2 + 0], v.x);
    atomicAdd(&agg[(size_t)dst * NHID_C + lane * 2 + 1], v.y);
}

// Phase 4a: xw2 = relu(agg1) @ W2 — wave per node, coalesced, shfl reduce.
__global__ __launch_bounds__(256) void k_gcn2(
    const float* __restrict__ agg1, const float* __restrict__ W2,
    float* __restrict__ xw2)
{
    const int wv = threadIdx.x >> 6, lane = threadIdx.x & 63;
    const int n = blockIdx.x * 4 + wv;
    if (n >= N_NODES_C) return;
    float2 a = *(const float2*)(agg1 + (size_t)n * NHID_C + lane * 2);
    a.x = a.x > 0.f ? a.x : 0.f;
    a.y = a.y > 0.f ? a.y : 0.f;
    const float4 w0 = *(const float4*)(W2 + lane * 8);
    const float4 w1 = *(const float4*)(W2 + lane * 8 + 4);
    float s0 = a.x * w0.x + a.y * w1.x;
    float s1 = a.x * w0.y + a.y * w1.y;
    float s2 = a.x * w0.z + a.y * w1.z;
    float s3 = a.x * w0.w + a.y * w1.w;
    #pragma unroll
    for (int off = 32; off >= 1; off >>= 1) {
        s0 += __shfl_xor(s0, off, 64);
        s1 += __shfl_xor(s1, off, 64);
        s2 += __shfl_xor(s2, off, 64);
        s3 += __shfl_xor(s3, off, 64);
    }
    if (lane == 0) *(float4*)(xw2 + (size_t)n * 4) = make_float4(s0, s1, s2, s3);
}

// Phase 4b: scatter-add xw2[src] into out[dst].
__global__ void k_scatter2(const float* __restrict__ xw2, const int* __restrict__ ei,
                           float* __restrict__ out)
{
    const int idx = blockIdx.x * 256 + threadIdx.x;
    const int e = idx >> 2, cc = idx & 3;
    if (e >= N_EDGES_C) return;
    const int src = ei[e], dst = ei[N_EDGES_C + e];
    atomicAdd(&out[(size_t)dst * 4 + cc], xw2[(size_t)src * 4 + cc]);
}

extern "C" void kernel_launch(void* const* d_in, const int* in_sizes, int n_in,
                              void* d_out, int out_size, void* d_ws, size_t ws_size,
                              hipStream_t stream) {
    const int*   sentence = (const int*)d_in[0];
    const int*   ei1      = (const int*)d_in[1];
    const int*   ei2      = (const int*)d_in[2];
    const float* emb      = (const float*)d_in[5];
    const float* Wih_f    = (const float*)d_in[6];
    const float* Whh_f    = (const float*)d_in[7];
    const float* b_f      = (const float*)d_in[8];
    const float* Wih_b    = (const float*)d_in[9];
    const float* Whh_b    = (const float*)d_in[10];
    const float* b_b      = (const float*)d_in[11];
    const float* W1       = (const float*)d_in[12];
    const float* W2       = (const float*)d_in[13];
    float* out = (float*)d_out;

    char* ws = (char*)d_ws;
    unsigned short* Tf = (unsigned short*)(ws);
    unsigned short* Tb = (unsigned short*)(ws + 51200000);
    float* X    = (float*)(ws + 102400000);
    float* xw1  = (float*)(ws);             // alias Tf (dead after k_lstm)
    float* agg1 = (float*)(ws + 25600000);  // alias Tf upper half
    float* xw2  = (float*)(ws + 51200000);  // alias Tb

    (void)hipFuncSetAttribute((const void*)k_table,
                              hipFuncAttributeMaxDynamicSharedMemorySize, 131072);
    (void)hipFuncSetAttribute((const void*)k_lstm,
                              hipFuncAttributeMaxDynamicSharedMemorySize, 131072);
    (void)hipFuncSetAttribute((const void*)k_gcn1,
                              hipFuncAttributeMaxDynamicSharedMemorySize, 131072);

    (void)hipMemsetAsync(out, 0, (size_t)N_NODES_C * 4 * sizeof(float), stream);

    k_table<<<dim3(391, 2), 256, 131072, stream>>>(emb, Wih_f, b_f, Wih_b, b_b, Tf, Tb);
    k_lstm<<<dim3(98, 2), 1024, 131072, stream>>>(sentence, Whh_f, Whh_b, Tf, Tb, X);
    k_gcn1<<<dim3(391), 256, 131072, stream>>>(X, W1, xw1);
    (void)hipMemsetAsync(agg1, 0, (size_t)N_NODES_C * NHID_C * sizeof(float), stream);
    k_scatter1<<<dim3(N_EDGES_C / 4), 256, 0, stream>>>(xw1, ei1, agg1);
    k_gcn2<<<dim3((N_NODES_C + 3) / 4), 256, 0, stream>>>(agg1, W2, xw2);
    k_scatter2<<<dim3(N_EDGES_C * 4 / 256), 256, 0, stream>>>(xw2, ei2, out);
}

// Round 15
// 1520.777 us; speedup vs baseline: 1.3608x; 1.3608x over previous
//
#include <hip/hip_runtime.h>

#define N_NODES_C 50000
#define SEQ_LEN_C 32
#define VOCAB_C 50000
#define EMBED_C 300
#define NHID_C 128
#define NGATE_C 512
#define N_EDGES_C 800000

typedef __attribute__((ext_vector_type(8))) short s16x8;
typedef __attribute__((ext_vector_type(16))) float f32x16;

#define LOG2E_C 1.442695040888963f

__device__ __forceinline__ unsigned f2bf(float x) {
    unsigned u = __float_as_uint(x);
    return (u + 0x7fffu + ((u >> 16) & 1u)) >> 16;
}
__device__ __forceinline__ float bf2f(unsigned h) { return __uint_as_float(h << 16); }
__device__ __forceinline__ float bflo(unsigned u) { return __uint_as_float(u << 16); }
__device__ __forceinline__ float bfhi(unsigned u) { return __uint_as_float(u & 0xffff0000u); }
__device__ __forceinline__ float rcp_f(float x) { return __builtin_amdgcn_rcpf(x); }
__device__ __forceinline__ float exp2_f(float x) { return __builtin_amdgcn_exp2f(x); }
__device__ __forceinline__ unsigned cvt_pk_bf16(float a, float b) {
    unsigned r;
    asm("v_cvt_pk_bf16_f32 %0, %1, %2" : "=v"(r) : "v"(a), "v"(b));
    return r;
}

// Gate-row permutation (k_table T layout + k_lstm Whh frags), 32x32 tiles:
// tile gt, row-in-tile rr: gate = rr&3, hh = rr>>2,
// hid = (gt>>1)*16 + (hh&1)*8 + (gt&1)*4 + (hh>>1), g_orig = gate*128 + hid.
// T slot layout is READER-register-ordered: slot(gt, hi, r) = gt*32 + hi*16 + r.
// => writer: off_c = gt*32 + ((hid>>3)&1)*16 + gate + 4*(hid&3).
// Reader loads 2 contiguous dwordx4 per tile (32B/lane).

// ---------------------------------------------------------------------------
// Phase 1: T[v] = permuted bf16 of emb[v] @ Wih^T + b. grid (391,2), 256 thr.
// Direct 2B scatter store (R13 form): L2 write-combining assembles full lines
// per 1KB vocab row -- the R14 LDS-staged variant was 160us SLOWER (1 blk/CU).
// ---------------------------------------------------------------------------
__global__ __launch_bounds__(256) void k_table(
    const float* __restrict__ emb,
    const float* __restrict__ WihF, const float* __restrict__ bF,
    const float* __restrict__ WihB, const float* __restrict__ bB,
    unsigned short* __restrict__ TF, unsigned short* __restrict__ TB)
{
    const int dir = blockIdx.y;
    const float* __restrict__ Wih  = dir ? WihB : WihF;
    const float* __restrict__ bias = dir ? bB : bF;
    unsigned short* __restrict__ T = dir ? TB : TF;

    const int tid = threadIdx.x;
    const int lane = tid & 63;
    const int lo = lane & 31, hi = lane >> 5;
    const int vbase = blockIdx.x * 128 + (tid >> 6) * 32;
    int vr = vbase + lo;
    if (vr >= VOCAB_C) vr = VOCAB_C - 1;

    s16x8 afr[19];
    #pragma unroll
    for (int kt = 0; kt < 19; ++kt) {
        const int k = kt * 16 + hi * 8;
        const float* src = emb + vr * EMBED_C + k;
        float4 a = *(const float4*)src;
        float4 b = (k + 8 <= EMBED_C) ? *(const float4*)(src + 4)
                                      : make_float4(0.f, 0.f, 0.f, 0.f);
        s16x8 f;
        f[0] = (short)f2bf(a.x); f[1] = (short)f2bf(a.y);
        f[2] = (short)f2bf(a.z); f[3] = (short)f2bf(a.w);
        f[4] = (short)f2bf(b.x); f[5] = (short)f2bf(b.y);
        f[6] = (short)f2bf(b.z); f[7] = (short)f2bf(b.w);
        afr[kt] = f;
    }

    for (int nt = 0; nt < 16; ++nt) {
        const int g = nt * 32 + lo;
        const float bv = bias[g];
        const int gate = g >> 7, hid = g & 127;
        const int gt = (hid >> 4) * 2 + ((hid >> 2) & 1);
        const int off_c = gt * 32 + ((hid >> 3) & 1) * 16 + gate + 4 * (hid & 3);
        f32x16 acc;
        #pragma unroll
        for (int r = 0; r < 16; ++r) acc[r] = bv;
        #pragma unroll
        for (int kt = 0; kt < 19; ++kt) {
            const int k = kt * 16 + hi * 8;
            const float* src = Wih + g * EMBED_C + k;
            float4 a = *(const float4*)src;
            float4 b = (k + 8 <= EMBED_C) ? *(const float4*)(src + 4)
                                          : make_float4(0.f, 0.f, 0.f, 0.f);
            s16x8 w;
            w[0] = (short)f2bf(a.x); w[1] = (short)f2bf(a.y);
            w[2] = (short)f2bf(a.z); w[3] = (short)f2bf(a.w);
            w[4] = (short)f2bf(b.x); w[5] = (short)f2bf(b.y);
            w[6] = (short)f2bf(b.z); w[7] = (short)f2bf(b.w);
            acc = __builtin_amdgcn_mfma_f32_32x32x16_bf16(afr[kt], w, acc, 0, 0, 0);
        }
        #pragma unroll
        for (int r = 0; r < 16; ++r) {
            const int v = vbase + (r & 3) + 8 * (r >> 2) + 4 * hi;
            if (v < VOCAB_C) T[(size_t)v * NGATE_C + off_c] = (unsigned short)f2bf(acc[r]);
        }
    }
}

// ---------------------------------------------------------------------------
// Phase 2: persistent LSTM (R13 form, plateaued ~950us).
// ---------------------------------------------------------------------------
__global__ __launch_bounds__(1024)
__attribute__((amdgpu_waves_per_eu(4, 4)))
void k_lstm(
    const int* __restrict__ sentence,
    const float* __restrict__ WhhF, const float* __restrict__ WhhB,
    const unsigned short* __restrict__ TF, const unsigned short* __restrict__ TB,
    float* __restrict__ X)
{
    extern __shared__ unsigned short lds[]; // 8192 slots * 16B = 128KB
    const int dir = blockIdx.y;
    const float* __restrict__ Whh = dir ? WhhB : WhhF;
    const unsigned short* __restrict__ T = dir ? TB : TF;
    const int tid = threadIdx.x;

    for (int s = tid; s < 8192; s += 1024) {
        const int ls = s & 63;
        const int gt = (s >> 6) & 15;
        const int kt = s >> 10;
        const int rr = ls & 31, khalf = ls >> 5;
        const int gate = rr & 3, hh = rr >> 2;
        const int hid = (gt >> 1) * 16 + (hh & 1) * 8 + (gt & 1) * 4 + (hh >> 1);
        const int g_orig = gate * NHID_C + hid;
        const int k = kt * 16 + khalf * 8;
        const float* src = Whh + g_orig * NHID_C + k;
        float4 a = *(const float4*)src;
        float4 b = *(const float4*)(src + 4);
        uint4 pk;
        pk.x = f2bf(a.x) | (f2bf(a.y) << 16);
        pk.y = f2bf(a.z) | (f2bf(a.w) << 16);
        pk.z = f2bf(b.x) | (f2bf(b.y) << 16);
        pk.w = f2bf(b.z) | (f2bf(b.w) << 16);
        *(uint4*)(lds + s * 8) = pk;
    }
    __syncthreads();

    const int lane = tid & 63;
    const int lo = lane & 31, hi = lane >> 5;
    const int node = blockIdx.x * 512 + (tid >> 6) * 32 + lo;
    const int nv = node < N_NODES_C ? node : 0;
    const int* __restrict__ sent = sentence + nv * SEQ_LEN_C;

    s16x8 hfr[8];
    #pragma unroll
    for (int kt = 0; kt < 8; ++kt) {
        #pragma unroll
        for (int j = 0; j < 8; ++j) hfr[kt][j] = 0;
    }
    unsigned cpk[32];
    #pragma unroll
    for (int r = 0; r < 32; ++r) cpk[r] = 0u;

    int wd = sent[dir ? 31 : 0];
    int wn = sent[dir ? 30 : 1];

    uint4 pf0, pf1;
    {
        const unsigned short* tr0 = T + (size_t)wd * NGATE_C + hi * 16;
        pf0 = *(const uint4*)(tr0);
        pf1 = *(const uint4*)(tr0 + 8);
    }

    for (int t = 0; t < SEQ_LEN_C - 1; ++t) {
        const unsigned short* trow = T + (size_t)wd * NGATE_C;
        const unsigned short* nrow = T + (size_t)wn * NGATE_C;
        wd = wn;
        const int nt2 = (t + 2 <= SEQ_LEN_C - 1) ? t + 2 : SEQ_LEN_C - 1;
        wn = sent[dir ? (SEQ_LEN_C - 1 - nt2) : nt2];
        uint4 nhf[8];

        #pragma unroll
        for (int gt = 0; gt < 16; ++gt) {
            f32x16 acc;
            acc[0]  = bflo(pf0.x); acc[1]  = bfhi(pf0.x);
            acc[2]  = bflo(pf0.y); acc[3]  = bfhi(pf0.y);
            acc[4]  = bflo(pf0.z); acc[5]  = bfhi(pf0.z);
            acc[6]  = bflo(pf0.w); acc[7]  = bfhi(pf0.w);
            acc[8]  = bflo(pf1.x); acc[9]  = bfhi(pf1.x);
            acc[10] = bflo(pf1.y); acc[11] = bfhi(pf1.y);
            acc[12] = bflo(pf1.z); acc[13] = bfhi(pf1.z);
            acc[14] = bflo(pf1.w); acc[15] = bfhi(pf1.w);
            const unsigned short* nsrc =
                ((gt < 15) ? (trow + (gt + 1) * 32) : nrow) + hi * 16;
            pf0 = *(const uint4*)(nsrc);
            pf1 = *(const uint4*)(nsrc + 8);

            #pragma unroll
            for (int kt = 0; kt < 8; ++kt) {
                const s16x8 af = *(const s16x8*)(lds + ((kt * 16 + gt) * 64 + lane) * 8);
                acc = __builtin_amdgcn_mfma_f32_32x32x16_bf16(af, hfr[kt], acc, 0, 0, 0);
            }

            const unsigned cp0 = cpk[gt * 2 + 0];
            const unsigned cp1 = cpk[gt * 2 + 1];
            const float cc[4] = {bflo(cp0), bfhi(cp0), bflo(cp1), bfhi(cp1)};
            float hn[4], cn[4];
            #pragma unroll
            for (int m = 0; m < 4; ++m) {
                const float iv = acc[4 * m + 0], fv = acc[4 * m + 1];
                const float gv = acc[4 * m + 2], ov = acc[4 * m + 3];
                const float a  = exp2_f(fv * -LOG2E_C);
                const float b  = exp2_f(iv * -LOG2E_C);
                const float G  = exp2_f(gv * (2.0f * LOG2E_C));
                const float oa = exp2_f(ov * -LOG2E_C);
                const float pa = 1.0f + a, pb = 1.0f + b;
                const float Gp = G + 1.0f, Gm = G - 1.0f;
                const float t0 = pb * Gp;
                const float num = __builtin_fmaf(cc[m], t0, pa * Gm);
                const float den = pa * t0;
                cn[m] = num * rcp_f(den);
                const float C  = exp2_f(cn[m] * (2.0f * LOG2E_C));
                hn[m] = (C - 1.0f) * rcp_f((1.0f + oa) * (C + 1.0f));
            }
            cpk[gt * 2 + 0] = cvt_pk_bf16(cn[0], cn[1]);
            cpk[gt * 2 + 1] = cvt_pk_bf16(cn[2], cn[3]);
            const unsigned w0 = cvt_pk_bf16(hn[0], hn[1]);
            const unsigned w1 = cvt_pk_bf16(hn[2], hn[3]);
            if ((gt & 1) == 0) { nhf[gt >> 1].x = w0; nhf[gt >> 1].y = w1; }
            else               { nhf[gt >> 1].z = w0; nhf[gt >> 1].w = w1; }
        }
        #pragma unroll
        for (int kt = 0; kt < 8; ++kt) hfr[kt] = *(s16x8*)&nhf[kt];
    }

    {
        const unsigned short* trow = T + (size_t)wd * NGATE_C;
        #pragma unroll
        for (int gt = 0; gt < 16; ++gt) {
            f32x16 acc;
            acc[0]  = bflo(pf0.x); acc[1]  = bfhi(pf0.x);
            acc[2]  = bflo(pf0.y); acc[3]  = bfhi(pf0.y);
            acc[4]  = bflo(pf0.z); acc[5]  = bfhi(pf0.z);
            acc[6]  = bflo(pf0.w); acc[7]  = bfhi(pf0.w);
            acc[8]  = bflo(pf1.x); acc[9]  = bfhi(pf1.x);
            acc[10] = bflo(pf1.y); acc[11] = bfhi(pf1.y);
            acc[12] = bflo(pf1.z); acc[13] = bfhi(pf1.z);
            acc[14] = bflo(pf1.w); acc[15] = bfhi(pf1.w);
            if (gt < 15) {
                const unsigned short* nsrc = trow + (gt + 1) * 32 + hi * 16;
                pf0 = *(const uint4*)(nsrc);
                pf1 = *(const uint4*)(nsrc + 8);
            }
            #pragma unroll
            for (int kt = 0; kt < 8; ++kt) {
                const s16x8 af = *(const s16x8*)(lds + ((kt * 16 + gt) * 64 + lane) * 8);
                acc = __builtin_amdgcn_mfma_f32_32x32x16_bf16(af, hfr[kt], acc, 0, 0, 0);
            }

            const unsigned cp0 = cpk[gt * 2 + 0];
            const unsigned cp1 = cpk[gt * 2 + 1];
            const float cc[4] = {bflo(cp0), bfhi(cp0), bflo(cp1), bfhi(cp1)};
            float hn[4];
            #pragma unroll
            for (int m = 0; m < 4; ++m) {
                const float iv = acc[4 * m + 0], fv = acc[4 * m + 1];
                const float gv = acc[4 * m + 2], ov = acc[4 * m + 3];
                const float a  = exp2_f(fv * -LOG2E_C);
                const float b  = exp2_f(iv * -LOG2E_C);
                const float G  = exp2_f(gv * (2.0f * LOG2E_C));
                const float oa = exp2_f(ov * -LOG2E_C);
                const float pa = 1.0f + a, pb = 1.0f + b;
                const float Gp = G + 1.0f, Gm = G - 1.0f;
                const float t0 = pb * Gp;
                const float num = __builtin_fmaf(cc[m], t0, pa * Gm);
                const float den = pa * t0;
                const float cnv = num * rcp_f(den);
                const float C  = exp2_f(cnv * (2.0f * LOG2E_C));
                hn[m] = (C - 1.0f) * rcp_f((1.0f + oa) * (C + 1.0f));
            }
            if (node < N_NODES_C) {
                *(float4*)(X + (size_t)node * 256 + dir * NHID_C
                           + (gt >> 1) * 16 + hi * 8 + (gt & 1) * 4)
                    = make_float4(hn[0], hn[1], hn[2], hn[3]);
            }
        }
    }
}

// ---------------------------------------------------------------------------
// Phase 3a: xw1 = X @ W1, split-bf16 (hi/lo) 3-MFMA. (unchanged)
// ---------------------------------------------------------------------------
__global__ __launch_bounds__(256) void k_gcn1(
    const float* __restrict__ X, const float* __restrict__ W1, float* __restrict__ xw1)
{
    extern __shared__ unsigned short lds[];
    const int tid = threadIdx.x;
    for (int idx = tid; idx < 4096; idx += 256) {
        const int kt = idx >> 8, nt = (idx >> 6) & 3, ls = idx & 63;
        const int k0 = kt * 16 + (ls >> 5) * 8;
        const int j = nt * 32 + (ls & 31);
        unsigned ph[8], pl[8];
        #pragma unroll
        for (int jj = 0; jj < 8; ++jj) {
            const float w = W1[(k0 + jj) * NHID_C + j];
            const unsigned wh = f2bf(w);
            ph[jj] = wh;
            pl[jj] = f2bf(w - bf2f(wh));
        }
        uint4 vh, vl;
        vh.x = ph[0] | (ph[1] << 16); vh.y = ph[2] | (ph[3] << 16);
        vh.z = ph[4] | (ph[5] << 16); vh.w = ph[6] | (ph[7] << 16);
        vl.x = pl[0] | (pl[1] << 16); vl.y = pl[2] | (pl[3] << 16);
        vl.z = pl[4] | (pl[5] << 16); vl.w = pl[6] | (pl[7] << 16);
        *(uint4*)(lds + idx * 8) = vh;
        *(uint4*)(lds + (4096 + idx) * 8) = vl;
    }
    __syncthreads();

    const int lane = tid & 63, lo = lane & 31, hi = lane >> 5;
    const int nbase = blockIdx.x * 128 + (tid >> 6) * 32;
    int nr = nbase + lo;
    if (nr >= N_NODES_C) nr = N_NODES_C - 1;

    f32x16 acc[4];
    #pragma unroll
    for (int nt = 0; nt < 4; ++nt) {
        #pragma unroll
        for (int r = 0; r < 16; ++r) acc[nt][r] = 0.f;
    }

    for (int kt = 0; kt < 16; ++kt) {
        const float* src = X + (size_t)nr * 256 + kt * 16 + hi * 8;
        float4 a = *(const float4*)src;
        float4 b = *(const float4*)(src + 4);
        float xv[8] = {a.x, a.y, a.z, a.w, b.x, b.y, b.z, b.w};
        s16x8 xh, xl;
        #pragma unroll
        for (int jj = 0; jj < 8; ++jj) {
            const unsigned h = f2bf(xv[jj]);
            xh[jj] = (short)h;
            xl[jj] = (short)f2bf(xv[jj] - bf2f(h));
        }
        #pragma unroll
        for (int nt = 0; nt < 4; ++nt) {
            const int slot = (kt * 4 + nt) * 64 + lane;
            const s16x8 bh = *(const s16x8*)(lds + slot * 8);
            const s16x8 bl = *(const s16x8*)(lds + (4096 + slot) * 8);
            acc[nt] = __builtin_amdgcn_mfma_f32_32x32x16_bf16(xh, bh, acc[nt], 0, 0, 0);
            acc[nt] = __builtin_amdgcn_mfma_f32_32x32x16_bf16(xl, bh, acc[nt], 0, 0, 0);
            acc[nt] = __builtin_amdgcn_mfma_f32_32x32x16_bf16(xh, bl, acc[nt], 0, 0, 0);
        }
    }
    #pragma unroll
    for (int nt = 0; nt < 4; ++nt) {
        #pragma unroll
        for (int r = 0; r < 16; ++r) {
            const int n = nbase + (r & 3) + 8 * (r >> 2) + 4 * hi;
            if (n < N_NODES_C) xw1[(size_t)n * NHID_C + nt * 32 + lo] = acc[nt][r];
        }
    }
}

// ---------------------------------------------------------------------------
// Phase 3b: CSR build (per call, deterministic) + fused gather/relu/W2.
// Replaces 102M f32 atomics + agg1 round-trip + k_gcn2.
// ---------------------------------------------------------------------------
__global__ void k_hist(const int* __restrict__ ei, int* __restrict__ cnt)
{
    const int e = blockIdx.x * 256 + threadIdx.x;
    if (e >= N_EDGES_C) return;
    atomicAdd(&cnt[ei[N_EDGES_C + e]], 1);
}

__global__ __launch_bounds__(1024) void k_scan(
    const int* __restrict__ cnt, int* __restrict__ offs)
{
    __shared__ int part[1024];
    const int tid = threadIdx.x;
    const int base = tid * 49;
    int s = 0;
    for (int j = 0; j < 49; ++j) {
        const int i = base + j;
        if (i < N_NODES_C) s += cnt[i];
    }
    part[tid] = s;
    __syncthreads();
    #pragma unroll
    for (int off = 1; off < 1024; off <<= 1) {
        int v = (tid >= off) ? part[tid - off] : 0;
        __syncthreads();
        part[tid] += v;
        __syncthreads();
    }
    int run = (tid == 0) ? 0 : part[tid - 1];
    for (int j = 0; j < 49; ++j) {
        const int i = base + j;
        if (i < N_NODES_C) { offs[i] = run; run += cnt[i]; }
    }
}

// bucket-scatter edge sources; offs becomes END offsets afterwards
__global__ void k_eid(const int* __restrict__ ei, int* __restrict__ offs,
                      int* __restrict__ srcs)
{
    const int e = blockIdx.x * 256 + threadIdx.x;
    if (e >= N_EDGES_C) return;
    const int dst = ei[N_EDGES_C + e];
    const int pos = atomicAdd(&offs[dst], 1);
    srcs[pos] = ei[e];
}

// wave per dst node: sum in-neighbor xw1 rows, relu, @W2, write xw2[n*4]
__global__ __launch_bounds__(256) void k_gather(
    const float* __restrict__ xw1, const int* __restrict__ srcs,
    const int* __restrict__ offs_end, const int* __restrict__ cnt,
    const float* __restrict__ W2, float* __restrict__ xw2)
{
    const int wv = threadIdx.x >> 6, lane = threadIdx.x & 63;
    const int n = blockIdx.x * 4 + wv;
    if (n >= N_NODES_C) return;
    const int end = offs_end[n];
    const int deg = cnt[n];
    float a0 = 0.f, a1 = 0.f;
    for (int p = end - deg; p < end; ++p) {
        const int s = srcs[p];
        const float2 v = *(const float2*)(xw1 + (size_t)s * NHID_C + lane * 2);
        a0 += v.x; a1 += v.y;
    }
    a0 = a0 > 0.f ? a0 : 0.f;
    a1 = a1 > 0.f ? a1 : 0.f;
    const float4 w0 = *(const float4*)(W2 + lane * 8);
    const float4 w1 = *(const float4*)(W2 + lane * 8 + 4);
    float s0 = a0 * w0.x + a1 * w1.x;
    float s1 = a0 * w0.y + a1 * w1.y;
    float s2 = a0 * w0.z + a1 * w1.z;
    float s3 = a0 * w0.w + a1 * w1.w;
    #pragma unroll
    for (int off = 32; off >= 1; off >>= 1) {
        s0 += __shfl_xor(s0, off, 64);
        s1 += __shfl_xor(s1, off, 64);
        s2 += __shfl_xor(s2, off, 64);
        s3 += __shfl_xor(s3, off, 64);
    }
    if (lane == 0) *(float4*)(xw2 + (size_t)n * 4) = make_float4(s0, s1, s2, s3);
}

// Phase 4b: scatter-add xw2[src] into out[dst].
__global__ void k_scatter2(const float* __restrict__ xw2, const int* __restrict__ ei,
                           float* __restrict__ out)
{
    const int idx = blockIdx.x * 256 + threadIdx.x;
    const int e = idx >> 2, cc = idx & 3;
    if (e >= N_EDGES_C) return;
    const int src = ei[e], dst = ei[N_EDGES_C + e];
    atomicAdd(&out[(size_t)dst * 4 + cc], xw2[(size_t)src * 4 + cc]);
}

extern "C" void kernel_launch(void* const* d_in, const int* in_sizes, int n_in,
                              void* d_out, int out_size, void* d_ws, size_t ws_size,
                              hipStream_t stream) {
    const int*   sentence = (const int*)d_in[0];
    const int*   ei1      = (const int*)d_in[1];
    const int*   ei2      = (const int*)d_in[2];
    const float* emb      = (const float*)d_in[5];
    const float* Wih_f    = (const float*)d_in[6];
    const float* Whh_f    = (const float*)d_in[7];
    const float* b_f      = (const float*)d_in[8];
    const float* Wih_b    = (const float*)d_in[9];
    const float* Whh_b    = (const float*)d_in[10];
    const float* b_b      = (const float*)d_in[11];
    const float* W1       = (const float*)d_in[12];
    const float* W2       = (const float*)d_in[13];
    float* out = (float*)d_out;

    char* ws = (char*)d_ws;
    unsigned short* Tf = (unsigned short*)(ws);
    unsigned short* Tb = (unsigned short*)(ws + 51200000);
    float* X    = (float*)(ws + 102400000);
    float* xw1  = (float*)(ws);              // alias Tf (dead after k_lstm)
    // CSR + xw2 live in the dead Tb region (dead after k_lstm):
    float* xw2  = (float*)(ws + 51200000);   // 800KB
    int*   cnt  = (int*)(ws + 56000000);     // 200KB
    int*   offs = (int*)(ws + 57000000);     // 200KB
    int*   srcs = (int*)(ws + 58000000);     // 3.2MB

    (void)hipFuncSetAttribute((const void*)k_lstm,
                              hipFuncAttributeMaxDynamicSharedMemorySize, 131072);
    (void)hipFuncSetAttribute((const void*)k_gcn1,
                              hipFuncAttributeMaxDynamicSharedMemorySize, 131072);

    (void)hipMemsetAsync(out, 0, (size_t)N_NODES_C * 4 * sizeof(float), stream);

    k_table<<<dim3(391, 2), 256, 0, stream>>>(emb, Wih_f, b_f, Wih_b, b_b, Tf, Tb);
    k_lstm<<<dim3(98, 2), 1024, 131072, stream>>>(sentence, Whh_f, Whh_b, Tf, Tb, X);
    k_gcn1<<<dim3(391), 256, 131072, stream>>>(X, W1, xw1);
    // CSR build for edge set 1 (Tb is dead now)
    (void)hipMemsetAsync(cnt, 0, (size_t)N_NODES_C * sizeof(int), stream);
    k_hist<<<dim3((N_EDGES_C + 255) / 256), 256, 0, stream>>>(ei1, cnt);
    k_scan<<<dim3(1), 1024, 0, stream>>>(cnt, offs);
    k_eid<<<dim3((N_EDGES_C + 255) / 256), 256, 0, stream>>>(ei1, offs, srcs);
    k_gather<<<dim3((N_NODES_C + 3) / 4), 256, 0, stream>>>(xw1, srcs, offs, cnt, W2, xw2);
    k_scatter2<<<dim3(N_EDGES_C * 4 / 256), 256, 0, stream>>>(xw2, ei2, out);
}